// Round 12
// baseline (182.917 us; speedup 1.0000x reference)
//
#include <hip/hip_runtime.h>
#include <stdint.h>

#define DI __device__ __forceinline__

// ---------------- workspace layout (bytes) ----------------
static constexpr size_t OFF_MAX  = 0;                     // int[4]: [0]x [1]t1 [2]t2 [3]u (memset-init'd)
static constexpr size_t OFF_WSC  = 64;                    // float[4] weight scales (idx 2 unused)
static constexpr size_t OFF_W1P  = 1024;                  // int[150]  conv1 w (c0,c1,c2,0) per tap
static constexpr size_t OFF_W2P  = 4096;                  // int[800]  conv2 w (c0..c3),(c4,c5,0,0) per tap
static constexpr size_t OFF_WS2  = 8192;                  // int[16]   conv2 per-oc weight sums
static constexpr size_t OFF_FW1B = 8704;                  // float[16] fw1 per-slice maxes (race-free)
static constexpr size_t OFF_FW2I = 212992;                // float[1200] fc2 int-valued weights
static constexpr size_t OFF_UF   = 262144;                // float[983040] fc1 output
static constexpr size_t OFF_T2F  = OFF_UF + 4194304ull;   // float[3276800] [B][400]
static constexpr size_t OFF_T1F  = OFF_UF + 20971520ull;  // float[9633792] [6][B][196]

#if defined(__HIP_DEVICE_COMPILE__) && __has_builtin(__builtin_amdgcn_sdot4)
#define HAS_SDOT4 1
#else
#define HAS_SDOT4 0
#endif

DI int dot4(int a, int b, int c) {
#if HAS_SDOT4
  return __builtin_amdgcn_sdot4(a, b, c, false);
#else
  c += ((int)(a << 24) >> 24) * ((int)(b << 24) >> 24);
  c += ((int)(a << 16) >> 24) * ((int)(b << 16) >> 24);
  c += ((int)(a << 8) >> 24) * ((int)(b << 8) >> 24);
  c += ((int)a >> 24) * ((int)b >> 24);
  return c;
#endif
}

DI float warpMax(float v) {
#pragma unroll
  for (int o = 32; o > 0; o >>= 1) v = fmaxf(v, __shfl_down(v, o, 64));
  return v;
}

DI float blockMax(float v) {  // valid on thread 0
  __shared__ float sm[8];
  int lane = threadIdx.x & 63, w = threadIdx.x >> 6;
  v = warpMax(v);
  if (lane == 0) sm[w] = v;
  __syncthreads();
  if (w == 0) {
    int nw = blockDim.x >> 6;
    v = (lane < nw) ? sm[lane] : 0.0f;
    v = warpMax(v);
  }
  return v;
}

DI int qclamp(float v, float s) {
  return (int)fminf(fmaxf(rintf(v / s), -128.0f), 127.0f);
}

DI uint32_t pack3(float a, float b, float c, float s) {
  int qa = qclamp(a, s), qb = qclamp(b, s), qc = qclamp(c, s);
  return (uint32_t)(qa & 255) | ((uint32_t)(qb & 255) << 8) | ((uint32_t)(qc & 255) << 16);
}

// ---- prep: [0,2048) x absmax -> atomicMax(mx[0]) (mx memset-init'd on stream
//      BEFORE this kernel -> no init race); [2048,2064) fw1 max slices -> fw1bm;
//      2064 = w1 max/pack; 2065 = w2 max/pack/wsum2; 2066 = fw2.
__global__ __launch_bounds__(256) void k_prep(const float4* __restrict__ x,
                                              const float* __restrict__ w1, const float* __restrict__ w2,
                                              const float* __restrict__ fw1, const float* __restrict__ fw2,
                                              int* __restrict__ mx, float* __restrict__ wsc,
                                              int* __restrict__ w1pi, int* __restrict__ w2pi,
                                              float* __restrict__ fw2i, int* __restrict__ wsum2,
                                              float* __restrict__ fw1bm) {
  int tid = threadIdx.x;
  int bid = blockIdx.x;
  if (bid < 2048) {
    const int n4 = 6291456;
    float m = 0.f;
    for (int i = bid * 256 + tid; i < n4; i += 2048 * 256) {
      float4 v = x[i];
      m = fmaxf(m, fmaxf(fmaxf(fabsf(v.x), fabsf(v.y)), fmaxf(fabsf(v.z), fabsf(v.w))));
    }
    m = blockMax(m);
    if (tid == 0) atomicMax(mx, __float_as_int(m));  // mx[0] pre-zeroed by memset
    return;
  }
  if (bid < 2064) {  // fw1 absmax, 16 parallel slices of 750 float4
    int sl = bid - 2048;
    const float4* f4 = (const float4*)fw1;
    float m = 0.f;
    for (int i = sl * 750 + tid; i < (sl + 1) * 750; i += 256) {
      float4 v = f4[i];
      m = fmaxf(m, fmaxf(fmaxf(fabsf(v.x), fabsf(v.y)), fmaxf(fabsf(v.z), fabsf(v.w))));
    }
    m = blockMax(m);
    if (tid == 0) fw1bm[sl] = m;  // race-free scratch
    return;
  }

  __shared__ float sbc;
  __shared__ int wsm[16];
  int wbid = bid - 2064;

  if (wbid == 0) {
    float m = 0.f;
    for (int i = tid; i < 450; i += 256) m = fmaxf(m, fabsf(w1[i]));
    m = blockMax(m);
    if (tid == 0) { sbc = m; wsc[0] = m / 127.0f + 1e-12f; }
    __syncthreads();
    float s = sbc / 127.0f + 1e-12f;
    if (tid < 150) {  // o*25 + tap -> (w_c0,w_c1,w_c2,0)
      int o = tid / 25, t = tid % 25;
      int q0 = qclamp(w1[o * 75 + 0 * 25 + t], s);
      int q1 = qclamp(w1[o * 75 + 1 * 25 + t], s);
      int q2 = qclamp(w1[o * 75 + 2 * 25 + t], s);
      w1pi[tid] = (q0 & 255) | ((q1 & 255) << 8) | ((q2 & 255) << 16);
    }
  } else if (wbid == 1) {
    float m = 0.0f;
    for (int i = tid; i < 2400; i += 256) m = fmaxf(m, fabsf(w2[i]));
    m = blockMax(m);
    if (tid == 0) { sbc = m; wsc[1] = m / 127.0f + 1e-12f; }
    if (tid < 16) wsm[tid] = 0;
    __syncthreads();
    float s = sbc / 127.0f + 1e-12f;
    for (int t0 = tid; t0 < 400; t0 += 256) {  // oc*25 + tap -> (c0..c3),(c4,c5,0,0)
      int o = t0 / 25, t = t0 % 25;
      int q0 = qclamp(w2[o * 150 + 0 * 25 + t], s);
      int q1 = qclamp(w2[o * 150 + 1 * 25 + t], s);
      int q2 = qclamp(w2[o * 150 + 2 * 25 + t], s);
      int q3 = qclamp(w2[o * 150 + 3 * 25 + t], s);
      int q4 = qclamp(w2[o * 150 + 4 * 25 + t], s);
      int q5 = qclamp(w2[o * 150 + 5 * 25 + t], s);
      w2pi[2 * t0] = (q0 & 255) | ((q1 & 255) << 8) | ((q2 & 255) << 16) | ((q3 & 255) << 24);
      w2pi[2 * t0 + 1] = (q4 & 255) | ((q5 & 255) << 8);
      atomicAdd(&wsm[o], q0 + q1 + q2 + q3 + q4 + q5);
    }
    __syncthreads();
    if (tid < 16) wsum2[tid] = wsm[tid];
  } else {
    float m = 0.0f;
    for (int i = tid; i < 1200; i += 256) m = fmaxf(m, fabsf(fw2[i]));
    m = blockMax(m);
    if (tid == 0) { sbc = m; wsc[3] = m / 127.0f + 1e-12f; }
    __syncthreads();
    float s = sbc / 127.0f + 1e-12f;
    for (int i = tid; i < 1200; i += 256)
      fw2i[i] = fminf(fmaxf(rintf(fw2[i] / s), -128.0f), 127.0f);
  }
}

// fused quantize-x + conv1 (R9 inner loop; s0 restored to uniform scalar read
// of mxf[0] — the R4-verified fast path; no per-block xbmax reduce).
__global__ __launch_bounds__(256, 6) void k_conv1x(const float4* __restrict__ x4, const int* __restrict__ w1pi,
                                                   const float* __restrict__ b1, const float* __restrict__ mxf,
                                                   const float* __restrict__ wsc, float* __restrict__ t1f,
                                                   int* __restrict__ mx1) {
  __shared__ int xl[4608];  // 4 img x 32 rows x 36 dwords (pad 4/row)
  int tid = threadIdx.x;
  int blk = blockIdx.x;
  float s0 = mxf[0] / 127.0f + 1e-12f;

  // phase 1: quantize own 4 images into LDS
  const float4* xb = x4 + (size_t)blk * 3072;  // 4 img * 768 float4
#pragma unroll
  for (int i = 0; i < 4; ++i) {
    int G = i * 256 + tid;  // 1024 px4-groups
    int img = G >> 8, p4 = G & 255;
    float4 va = xb[img * 768 + p4];
    float4 vb = xb[img * 768 + 256 + p4];
    float4 vc = xb[img * 768 + 512 + p4];
    int4 o;
    o.x = (int)pack3(va.x, vb.x, vc.x, s0);
    o.y = (int)pack3(va.y, vb.y, vc.y, s0);
    o.z = (int)pack3(va.z, vb.z, vc.z, s0);
    o.w = (int)pack3(va.w, vb.w, vc.w, s0);
    int row = p4 >> 3, cg = p4 & 7;
    *(int4*)&xl[img * 1152 + row * 36 + cg * 4] = o;
  }
  __syncthreads();

  float s = s0 * wsc[0];
  float bq[6];
#pragma unroll
  for (int o = 0; o < 6; ++o) bq[o] = rintf(b1[o] / s) * s;

  float lmax = 0.f;
  for (int it = 0; it < 4; ++it) {
    int u = it * 256 + tid;  // 784 units = 4 img x 14 ph x 14 pw
    if (u < 784) {
      int img = u / 196, rem = u % 196;
      int ph = rem / 14, pw = rem % 14;
      const int* xbase = &xl[img * 1152 + ph * 72 + pw * 2];
      int p[6][6];
#pragma unroll
      for (int r = 0; r < 6; ++r) {
        int2 a0 = *(const int2*)(xbase + r * 36);
        int2 a1 = *(const int2*)(xbase + r * 36 + 2);
        int2 a2 = *(const int2*)(xbase + r * 36 + 4);
        p[r][0] = a0.x; p[r][1] = a0.y; p[r][2] = a1.x;
        p[r][3] = a1.y; p[r][4] = a2.x; p[r][5] = a2.y;
      }
      int bg = blk * 4 + img;
#pragma unroll
      for (int o = 0; o < 6; ++o) {
        const int* wp = w1pi + o * 25;  // uniform -> s_load
        int aA0 = 0, aA1 = 0, aB0 = 0, aB1 = 0;
#pragma unroll
        for (int r = 0; r < 6; ++r) {
#pragma unroll
          for (int tc = 0; tc < 5; ++tc) {
            if (r <= 4) {
              int w = wp[r * 5 + tc];
              aA0 = dot4(p[r][tc], w, aA0);
              aA1 = dot4(p[r][tc + 1], w, aA1);
            }
            if (r >= 1) {
              int w = wp[(r - 1) * 5 + tc];
              aB0 = dot4(p[r][tc], w, aB0);
              aB1 = dot4(p[r][tc + 1], w, aB1);
            }
          }
        }
        int m0 = max(max(aA0, aA1), max(aB0, aB1));
        float v0 = fmaxf((float)m0 * s + bq[o], 0.f);
        t1f[(size_t)(o * 8192 + bg) * 196 + ph * 14 + pw] = v0;
        lmax = fmaxf(lmax, v0);
      }
    }
  }
  lmax = blockMax(lmax);
  if (tid == 0) atomicMax(mx1, __float_as_int(lmax));
}

// fused quantize-t1 + conv2: block = 16 images (R2-verified).
__global__ __launch_bounds__(256, 4) void k_conv2q(const float* __restrict__ t1f, const int* __restrict__ w2pi,
                                                   const float* __restrict__ b2, const float* __restrict__ mxf,
                                                   const float* __restrict__ wsc, const int* __restrict__ wsum2,
                                                   float* __restrict__ t2fb, int* __restrict__ mx2) {
  __shared__ char t1l[25344];  // 16 img x 1584 (14*112 + 16 pad)
  __shared__ int w2l[800];
  __shared__ int ws2l[16];
  int tid = threadIdx.x, blk = blockIdx.x;
  for (int i = tid; i < 800; i += 256) w2l[i] = w2pi[i];
  if (tid < 16) ws2l[tid] = wsum2[tid];

  float s1 = mxf[1] / 255.0f + 1e-12f;
  int b0 = blk * 16;
  const float4* tf = (const float4*)t1f;
  for (int it = 0; it < 19; ++it) {
    int g = it * 256 + tid;  // 4704 float4
    if (g < 4704) {
      int oc = g / 784, rem = g % 784;
      int img = rem / 49, f4 = rem % 49;
      float4 v = tf[(size_t)(oc * 8192 + b0 + img) * 49 + f4];
      int pos = f4 * 4;
      float vv[4] = {v.x, v.y, v.z, v.w};
#pragma unroll
      for (int c = 0; c < 4; ++c) {
        int pp = pos + c;
        int row = pp / 14, px = pp - row * 14;
        int q = (int)fminf(fmaxf(rintf(vv[c] / s1), 0.f), 255.f) - 128;
        t1l[img * 1584 + row * 112 + px * 8 + oc] = (char)q;
      }
    }
  }
  __syncthreads();

  float s = s1 * wsc[1];
  float lmax = 0.f;
  for (int it = 0; it < 3; ++it) {
    int u = it * 256 + tid;  // 640 units: pair fastest -> weight-LDS broadcast
    if (u < 640) {
      int pair = u & 7;
      int t = u >> 3;
      int ph = t % 5, img = t / 5;
      const char* base = &t1l[img * 1584 + ph * 224];
      int aA[2][10], aB[2][10];
#pragma unroll
      for (int g = 0; g < 2; ++g)
#pragma unroll
        for (int j = 0; j < 10; ++j) { aA[g][j] = 0; aB[g][j] = 0; }

#pragma unroll 1
      for (int r = 0; r < 6; ++r) {
        int p2[28];
        const uint4* rp = (const uint4*)(base + r * 112);
#pragma unroll
        for (int q = 0; q < 7; ++q) {
          uint4 uu = rp[q];
          p2[4 * q] = (int)uu.x; p2[4 * q + 1] = (int)uu.y;
          p2[4 * q + 2] = (int)uu.z; p2[4 * q + 3] = (int)uu.w;
        }
        if (r <= 4) {
#pragma unroll
          for (int tc = 0; tc < 5; ++tc) {
#pragma unroll
            for (int g = 0; g < 2; ++g) {
              int2 w = *(const int2*)&w2l[(pair * 2 + g) * 50 + r * 10 + 2 * tc];
#pragma unroll
              for (int j = 0; j < 10; ++j)
                aA[g][j] = dot4(p2[2 * (j + tc) + 1], w.y, dot4(p2[2 * (j + tc)], w.x, aA[g][j]));
            }
          }
        }
        if (r >= 1) {
#pragma unroll
          for (int tc = 0; tc < 5; ++tc) {
#pragma unroll
            for (int g = 0; g < 2; ++g) {
              int2 w = *(const int2*)&w2l[(pair * 2 + g) * 50 + (r - 1) * 10 + 2 * tc];
#pragma unroll
              for (int j = 0; j < 10; ++j)
                aB[g][j] = dot4(p2[2 * (j + tc) + 1], w.y, dot4(p2[2 * (j + tc)], w.x, aB[g][j]));
            }
          }
        }
      }
      int bg = b0 + img;
#pragma unroll
      for (int g = 0; g < 2; ++g) {
        int oc = pair * 2 + g;
        int off = 128 * ws2l[oc];  // un-centering
        float bq = rintf(b2[oc] / s) * s;
        float* orow = t2fb + (size_t)bg * 400 + oc * 25 + ph * 5;
#pragma unroll
        for (int j = 0; j < 5; ++j) {
          int m4 = max(max(aA[g][2 * j], aA[g][2 * j + 1]), max(aB[g][2 * j], aB[g][2 * j + 1]));
          float v = fmaxf((float)(m4 + off) * s + bq, 0.f);
          orow[j] = v;
          lmax = fmaxf(lmax, v);
        }
      }
    }
  }
  lmax = blockMax(lmax);
  if (tid == 0) atomicMax(mx2, __float_as_int(lmax));
}

// fused quantize-t2 + fc1 (R9-verified): stages fw1 raw floats inline, per-oc
// sums via dot4 rows, block = 32 images, grid 256.
__global__ __launch_bounds__(256) void k_fc1q(const float* __restrict__ t2fb, const float* __restrict__ fw1,
                                              const float* __restrict__ fb1, const float* __restrict__ mxf,
                                              const float* __restrict__ fw1bm, float* __restrict__ u,
                                              int* __restrict__ mx3) {
  __shared__ int wl[12000];  // 120 x 100 dwords
  __shared__ int xq[3200];   // 32 img x 100 dwords
  __shared__ int wsl[120];
  __shared__ float fwssh;
  int tid = threadIdx.x, blk = blockIdx.x;

  if (tid < 64) {  // reduce 16 slice maxes (identity 0 for lanes >= 16)
    float m = (tid < 16) ? fw1bm[tid] : 0.f;
    m = warpMax(m);
    if (tid == 0) fwssh = m / 127.0f + 1e-12f;
  }
  __syncthreads();
  float fws = fwssh;

  // stage + quantize fw1 (192 KB, L2-resident) into LDS
  const float4* w4 = (const float4*)fw1;
  for (int i = tid; i < 12000; i += 256) {
    float4 v = w4[i];
    int q0 = qclamp(v.x, fws), q1 = qclamp(v.y, fws), q2 = qclamp(v.z, fws), q3 = qclamp(v.w, fws);
    wl[i] = (q0 & 255) | ((q1 & 255) << 8) | ((q2 & 255) << 16) | ((q3 & 255) << 24);
  }

  float s2 = mxf[2] / 255.0f + 1e-12f;
  int b0 = blk * 32;
  const float4* tf = (const float4*)t2fb + (size_t)b0 * 100;
  for (int it = 0; it < 13; ++it) {
    int g = it * 256 + tid;  // 3200 float4
    if (g < 3200) {
      float4 v = tf[g];
      int q0 = (int)fminf(fmaxf(rintf(v.x / s2), 0.f), 255.f) - 128;
      int q1 = (int)fminf(fmaxf(rintf(v.y / s2), 0.f), 255.f) - 128;
      int q2 = (int)fminf(fmaxf(rintf(v.z / s2), 0.f), 255.f) - 128;
      int q3 = (int)fminf(fmaxf(rintf(v.w / s2), 0.f), 255.f) - 128;
      xq[g] = (q0 & 255) | ((q1 & 255) << 8) | ((q2 & 255) << 16) | ((q3 & 255) << 24);
    }
  }
  __syncthreads();

  if (tid < 120) {  // per-oc weight sum: own row, no atomics (exact int sum)
    int acc = 0;
    const int* row = &wl[tid * 100];
#pragma unroll
    for (int c = 0; c < 100; c += 4) {
      int4 wv = *(const int4*)&row[c];
      acc = dot4(wv.x, 0x01010101, acc);
      acc = dot4(wv.y, 0x01010101, acc);
      acc = dot4(wv.z, 0x01010101, acc);
      acc = dot4(wv.w, 0x01010101, acc);
    }
    wsl[tid] = acc;
  }
  __syncthreads();

  float s = s2 * fws;
  int img8 = tid >> 3, j = tid & 7;  // thread = (img, oc-lane)
  int acc[15];
#pragma unroll
  for (int seg = 0; seg < 15; ++seg) acc[seg] = 0;
#pragma unroll 1
  for (int kc = 0; kc < 5; ++kc) {
    int xr[20];
#pragma unroll
    for (int q = 0; q < 5; ++q) {
      int4 t = *(const int4*)&xq[img8 * 100 + kc * 20 + q * 4];
      xr[4 * q] = t.x; xr[4 * q + 1] = t.y; xr[4 * q + 2] = t.z; xr[4 * q + 3] = t.w;
    }
#pragma unroll
    for (int seg = 0; seg < 15; ++seg) {
      const int* wrow = &wl[(seg * 8 + j) * 100 + kc * 20];
#pragma unroll
      for (int q = 0; q < 20; q += 4) {
        int4 wv = *(const int4*)&wrow[q];
        acc[seg] = dot4(xr[q], wv.x, acc[seg]);
        acc[seg] = dot4(xr[q + 1], wv.y, acc[seg]);
        acc[seg] = dot4(xr[q + 2], wv.z, acc[seg]);
        acc[seg] = dot4(xr[q + 3], wv.w, acc[seg]);
      }
    }
  }
  float lmax = 0.f;
  int bg = b0 + img8;
#pragma unroll
  for (int seg = 0; seg < 15; ++seg) {
    int oc = seg * 8 + j;
    int tot = acc[seg] + 128 * wsl[oc];
    float bq = rintf(fb1[oc] / s) * s;
    float v = fmaxf((float)tot * s + bq, 0.f);
    u[(size_t)bg * 120 + oc] = v;
    lmax = fmaxf(lmax, v);
  }
  lmax = blockMax(lmax);
  if (tid == 0) atomicMax(mx3, __float_as_int(lmax));
}

// fc2: quantize u inline, * fw2i[10,120] -> out[B,10]. 128 blocks x 64.
__global__ __launch_bounds__(64) void k_fc2(const float* __restrict__ u, const float* __restrict__ fw2i,
                                            const float* __restrict__ fb2, const float* __restrict__ mxf,
                                            const float* __restrict__ wsc, float* __restrict__ out) {
  int b = blockIdx.x * 64 + threadIdx.x;
  float s3 = mxf[3] / 255.0f + 1e-12f;
  float s = s3 * wsc[3];
  float acc[10];
#pragma unroll
  for (int o = 0; o < 10; ++o) acc[o] = 0.f;
  const float4* ur = (const float4*)(u + (size_t)b * 120);
  for (int kk = 0; kk < 30; ++kk) {
    float4 v = ur[kk];
    float q0 = fminf(fmaxf(rintf(v.x / s3), 0.f), 255.f);
    float q1 = fminf(fmaxf(rintf(v.y / s3), 0.f), 255.f);
    float q2 = fminf(fmaxf(rintf(v.z / s3), 0.f), 255.f);
    float q3 = fminf(fmaxf(rintf(v.w / s3), 0.f), 255.f);
#pragma unroll
    for (int o = 0; o < 10; ++o) {
      const float4* wr = (const float4*)(fw2i + o * 120 + kk * 4);
      float4 wv = wr[0];
      acc[o] = fmaf(q0, wv.x, acc[o]);
      acc[o] = fmaf(q1, wv.y, acc[o]);
      acc[o] = fmaf(q2, wv.z, acc[o]);
      acc[o] = fmaf(q3, wv.w, acc[o]);
    }
  }
#pragma unroll
  for (int o = 0; o < 10; ++o) {
    float bq = rintf(fb2[o] / s) * s;
    out[(size_t)b * 10 + o] = acc[o] * s + bq;
  }
}

extern "C" void kernel_launch(void* const* d_in, const int* in_sizes, int n_in,
                              void* d_out, int out_size, void* d_ws, size_t ws_size,
                              hipStream_t stream) {
  const float* x = (const float*)d_in[0];
  const float* w1 = (const float*)d_in[1];
  const float* b1 = (const float*)d_in[2];
  const float* w2 = (const float*)d_in[3];
  const float* b2 = (const float*)d_in[4];
  const float* fw1 = (const float*)d_in[5];
  const float* fb1 = (const float*)d_in[6];
  const float* fw2 = (const float*)d_in[7];
  const float* fb2 = (const float*)d_in[8];

  char* ws = (char*)d_ws;
  int* mx = (int*)(ws + OFF_MAX);
  float* mxf = (float*)(ws + OFF_MAX);
  float* wsc = (float*)(ws + OFF_WSC);
  int* w1pi = (int*)(ws + OFF_W1P);
  int* w2pi = (int*)(ws + OFF_W2P);
  int* wsum2 = (int*)(ws + OFF_WS2);
  float* fw1bm = (float*)(ws + OFF_FW1B);
  float* fw2i = (float*)(ws + OFF_FW2I);
  float* uf = (float*)(ws + OFF_UF);
  float* t2fb = (float*)(ws + OFF_T2F);
  float* t1f = (float*)(ws + OFF_T1F);
  float* out = (float*)d_out;

  hipMemsetAsync(mx, 0, 16, stream);  // init atomic-max slots (graph-capture-safe)
  k_prep<<<2067, 256, 0, stream>>>((const float4*)x, w1, w2, fw1, fw2, mx, wsc,
                                   w1pi, w2pi, fw2i, wsum2, fw1bm);
  k_conv1x<<<2048, 256, 0, stream>>>((const float4*)x, w1pi, b1, mxf, wsc, t1f, mx + 1);
  k_conv2q<<<512, 256, 0, stream>>>(t1f, w2pi, b2, mxf, wsc, wsum2, t2fb, mx + 2);
  k_fc1q<<<256, 256, 0, stream>>>(t2fb, fw1, fb1, mxf, fw1bm, uf, mx + 3);
  k_fc2<<<128, 64, 0, stream>>>(uf, fw2i, fb2, mxf, wsc, out);
}

// Round 13
// 158.231 us; speedup vs baseline: 1.1560x; 1.1560x over previous
//
#include <hip/hip_runtime.h>
#include <stdint.h>

#define DI __device__ __forceinline__

// ---------------- workspace layout (bytes) ----------------
static constexpr size_t OFF_MAX  = 0;                     // int[4]: [1]t1 [2]t2 [3]u
static constexpr size_t OFF_WSC  = 64;                    // float[4] weight scales (idx 2 unused)
static constexpr size_t OFF_W1P  = 1024;                  // int[150]  conv1 w (c0,c1,c2,0) per tap
static constexpr size_t OFF_W2P  = 4096;                  // int[800]  conv2 w (c0..c3),(c4,c5,0,0) per tap
static constexpr size_t OFF_WS2  = 8192;                  // int[16]   conv2 per-oc weight sums
static constexpr size_t OFF_FW1B = 8704;                  // float[16] fw1 per-slice maxes (race-free)
static constexpr size_t OFF_FW2I = 212992;                // float[1200] fc2 int-valued weights
static constexpr size_t OFF_XBM  = 221184;                // float[1024] per-block |x| maxes (race-free)
static constexpr size_t OFF_UF   = 262144;                // float[983040] fc1 output
static constexpr size_t OFF_T2F  = OFF_UF + 4194304ull;   // float[3276800] [B][400]
static constexpr size_t OFF_T1F  = OFF_UF + 20971520ull;  // float[9633792] [6][B][196]

#if defined(__HIP_DEVICE_COMPILE__) && __has_builtin(__builtin_amdgcn_sdot4)
#define HAS_SDOT4 1
#else
#define HAS_SDOT4 0
#endif

DI int dot4(int a, int b, int c) {
#if HAS_SDOT4
  return __builtin_amdgcn_sdot4(a, b, c, false);
#else
  c += ((int)(a << 24) >> 24) * ((int)(b << 24) >> 24);
  c += ((int)(a << 16) >> 24) * ((int)(b << 16) >> 24);
  c += ((int)(a << 8) >> 24) * ((int)(b << 8) >> 24);
  c += ((int)a >> 24) * ((int)b >> 24);
  return c;
#endif
}

DI float warpMax(float v) {
#pragma unroll
  for (int o = 32; o > 0; o >>= 1) v = fmaxf(v, __shfl_down(v, o, 64));
  return v;
}

DI float blockMax(float v) {  // valid on thread 0
  __shared__ float sm[8];
  int lane = threadIdx.x & 63, w = threadIdx.x >> 6;
  v = warpMax(v);
  if (lane == 0) sm[w] = v;
  __syncthreads();
  if (w == 0) {
    int nw = blockDim.x >> 6;
    v = (lane < nw) ? sm[lane] : 0.0f;
    v = warpMax(v);
  }
  return v;
}

DI int qclamp(float v, float s) {
  return (int)fminf(fmaxf(rintf(v / s), -128.0f), 127.0f);
}

DI uint32_t pack3(float a, float b, float c, float s) {
  int qa = qclamp(a, s), qb = qclamp(b, s), qc = qclamp(c, s);
  return (uint32_t)(qa & 255) | ((uint32_t)(qb & 255) << 8) | ((uint32_t)(qc & 255) << 16);
}

// ---- prep: [0,1024) x absmax -> xbmax[] (race-free, 2x data per block);
//      [1024,1040) fw1 max slices -> fw1bm; 1040 = mx init + w1 max/pack;
//      1041 = w2 max/pack/wsum2; 1042 = fw2. (R9-verified structure; NO memset,
//      NO global atomics for x-max -- R11 showed the memset path costs ~20us.)
__global__ __launch_bounds__(256) void k_prep(const float4* __restrict__ x,
                                              const float* __restrict__ w1, const float* __restrict__ w2,
                                              const float* __restrict__ fw1, const float* __restrict__ fw2,
                                              int* __restrict__ mx, float* __restrict__ wsc,
                                              int* __restrict__ w1pi, int* __restrict__ w2pi,
                                              float* __restrict__ fw2i, int* __restrict__ wsum2,
                                              float* __restrict__ fw1bm, float* __restrict__ xbmax) {
  int tid = threadIdx.x;
  int bid = blockIdx.x;
  if (bid < 1024) {
    const int n4 = 6291456;
    float m = 0.f;
    for (int i = bid * 256 + tid; i < n4; i += 1024 * 256) {
      float4 v = x[i];
      m = fmaxf(m, fmaxf(fmaxf(fabsf(v.x), fabsf(v.y)), fmaxf(fabsf(v.z), fabsf(v.w))));
    }
    m = blockMax(m);
    if (tid == 0) xbmax[bid] = m;  // every slot written -> no init, no atomics
    return;
  }
  if (bid < 1040) {  // fw1 absmax, 16 parallel slices of 750 float4
    int sl = bid - 1024;
    const float4* f4 = (const float4*)fw1;
    float m = 0.f;
    for (int i = sl * 750 + tid; i < (sl + 1) * 750; i += 256) {
      float4 v = f4[i];
      m = fmaxf(m, fmaxf(fmaxf(fabsf(v.x), fabsf(v.y)), fmaxf(fabsf(v.z), fabsf(v.w))));
    }
    m = blockMax(m);
    if (tid == 0) fw1bm[sl] = m;  // race-free scratch
    return;
  }

  __shared__ float sbc;
  __shared__ int wsm[16];
  int wbid = bid - 1040;

  if (wbid == 0) {
    if (tid < 4) mx[tid] = 0;  // init running activation maxes (t1, t2, u)
    float m = 0.f;
    for (int i = tid; i < 450; i += 256) m = fmaxf(m, fabsf(w1[i]));
    m = blockMax(m);
    if (tid == 0) { sbc = m; wsc[0] = m / 127.0f + 1e-12f; }
    __syncthreads();
    float s = sbc / 127.0f + 1e-12f;
    if (tid < 150) {  // o*25 + tap -> (w_c0,w_c1,w_c2,0)
      int o = tid / 25, t = tid % 25;
      int q0 = qclamp(w1[o * 75 + 0 * 25 + t], s);
      int q1 = qclamp(w1[o * 75 + 1 * 25 + t], s);
      int q2 = qclamp(w1[o * 75 + 2 * 25 + t], s);
      w1pi[tid] = (q0 & 255) | ((q1 & 255) << 8) | ((q2 & 255) << 16);
    }
  } else if (wbid == 1) {
    float m = 0.0f;
    for (int i = tid; i < 2400; i += 256) m = fmaxf(m, fabsf(w2[i]));
    m = blockMax(m);
    if (tid == 0) { sbc = m; wsc[1] = m / 127.0f + 1e-12f; }
    if (tid < 16) wsm[tid] = 0;
    __syncthreads();
    float s = sbc / 127.0f + 1e-12f;
    for (int t0 = tid; t0 < 400; t0 += 256) {  // oc*25 + tap -> (c0..c3),(c4,c5,0,0)
      int o = t0 / 25, t = t0 % 25;
      int q0 = qclamp(w2[o * 150 + 0 * 25 + t], s);
      int q1 = qclamp(w2[o * 150 + 1 * 25 + t], s);
      int q2 = qclamp(w2[o * 150 + 2 * 25 + t], s);
      int q3 = qclamp(w2[o * 150 + 3 * 25 + t], s);
      int q4 = qclamp(w2[o * 150 + 4 * 25 + t], s);
      int q5 = qclamp(w2[o * 150 + 5 * 25 + t], s);
      w2pi[2 * t0] = (q0 & 255) | ((q1 & 255) << 8) | ((q2 & 255) << 16) | ((q3 & 255) << 24);
      w2pi[2 * t0 + 1] = (q4 & 255) | ((q5 & 255) << 8);
      atomicAdd(&wsm[o], q0 + q1 + q2 + q3 + q4 + q5);
    }
    __syncthreads();
    if (tid < 16) wsum2[tid] = wsm[tid];
  } else {
    float m = 0.0f;
    for (int i = tid; i < 1200; i += 256) m = fmaxf(m, fabsf(fw2[i]));
    m = blockMax(m);
    if (tid == 0) { sbc = m; wsc[3] = m / 127.0f + 1e-12f; }
    __syncthreads();
    float s = sbc / 127.0f + 1e-12f;
    for (int i = tid; i < 1200; i += 256)
      fw2i[i] = fminf(fmaxf(rintf(fw2[i] / s), -128.0f), 127.0f);
  }
}

// fused quantize-x + conv1 (R9 inner loop). Prologue reduces xbmax[1024] -> s0
// (4 loads/thread from 4KB L2-hot scratch -- was 2048/8 in R9, ~3.5us cheaper).
__global__ __launch_bounds__(256, 6) void k_conv1x(const float4* __restrict__ x4, const int* __restrict__ w1pi,
                                                   const float* __restrict__ b1, const float* __restrict__ xbmax,
                                                   const float* __restrict__ wsc, float* __restrict__ t1f,
                                                   int* __restrict__ mx1) {
  __shared__ int xl[4608];  // 4 img x 32 rows x 36 dwords (pad 4/row)
  __shared__ float s0sh;
  int tid = threadIdx.x;
  int blk = blockIdx.x;

  float mxv = 0.f;
#pragma unroll
  for (int i = 0; i < 4; ++i) mxv = fmaxf(mxv, xbmax[i * 256 + tid]);
  mxv = blockMax(mxv);
  if (tid == 0) s0sh = mxv / 127.0f + 1e-12f;
  __syncthreads();
  float s0 = s0sh;

  // phase 1: quantize own 4 images into LDS
  const float4* xb = x4 + (size_t)blk * 3072;  // 4 img * 768 float4
#pragma unroll
  for (int i = 0; i < 4; ++i) {
    int G = i * 256 + tid;  // 1024 px4-groups
    int img = G >> 8, p4 = G & 255;
    float4 va = xb[img * 768 + p4];
    float4 vb = xb[img * 768 + 256 + p4];
    float4 vc = xb[img * 768 + 512 + p4];
    int4 o;
    o.x = (int)pack3(va.x, vb.x, vc.x, s0);
    o.y = (int)pack3(va.y, vb.y, vc.y, s0);
    o.z = (int)pack3(va.z, vb.z, vc.z, s0);
    o.w = (int)pack3(va.w, vb.w, vc.w, s0);
    int row = p4 >> 3, cg = p4 & 7;
    *(int4*)&xl[img * 1152 + row * 36 + cg * 4] = o;
  }
  __syncthreads();

  float s = s0 * wsc[0];
  float bq[6];
#pragma unroll
  for (int o = 0; o < 6; ++o) bq[o] = rintf(b1[o] / s) * s;

  float lmax = 0.f;
  for (int it = 0; it < 4; ++it) {
    int u = it * 256 + tid;  // 784 units = 4 img x 14 ph x 14 pw
    if (u < 784) {
      int img = u / 196, rem = u % 196;
      int ph = rem / 14, pw = rem % 14;
      const int* xbase = &xl[img * 1152 + ph * 72 + pw * 2];
      int p[6][6];
#pragma unroll
      for (int r = 0; r < 6; ++r) {
        int2 a0 = *(const int2*)(xbase + r * 36);
        int2 a1 = *(const int2*)(xbase + r * 36 + 2);
        int2 a2 = *(const int2*)(xbase + r * 36 + 4);
        p[r][0] = a0.x; p[r][1] = a0.y; p[r][2] = a1.x;
        p[r][3] = a1.y; p[r][4] = a2.x; p[r][5] = a2.y;
      }
      int bg = blk * 4 + img;
#pragma unroll
      for (int o = 0; o < 6; ++o) {
        const int* wp = w1pi + o * 25;  // uniform -> s_load
        int aA0 = 0, aA1 = 0, aB0 = 0, aB1 = 0;
#pragma unroll
        for (int r = 0; r < 6; ++r) {
#pragma unroll
          for (int tc = 0; tc < 5; ++tc) {
            if (r <= 4) {
              int w = wp[r * 5 + tc];
              aA0 = dot4(p[r][tc], w, aA0);
              aA1 = dot4(p[r][tc + 1], w, aA1);
            }
            if (r >= 1) {
              int w = wp[(r - 1) * 5 + tc];
              aB0 = dot4(p[r][tc], w, aB0);
              aB1 = dot4(p[r][tc + 1], w, aB1);
            }
          }
        }
        int m0 = max(max(aA0, aA1), max(aB0, aB1));
        float v0 = fmaxf((float)m0 * s + bq[o], 0.f);
        t1f[(size_t)(o * 8192 + bg) * 196 + ph * 14 + pw] = v0;
        lmax = fmaxf(lmax, v0);
      }
    }
  }
  lmax = blockMax(lmax);
  if (tid == 0) atomicMax(mx1, __float_as_int(lmax));
}

// fused quantize-t1 + conv2: block = 16 images (R2-verified).
__global__ __launch_bounds__(256, 4) void k_conv2q(const float* __restrict__ t1f, const int* __restrict__ w2pi,
                                                   const float* __restrict__ b2, const float* __restrict__ mxf,
                                                   const float* __restrict__ wsc, const int* __restrict__ wsum2,
                                                   float* __restrict__ t2fb, int* __restrict__ mx2) {
  __shared__ char t1l[25344];  // 16 img x 1584 (14*112 + 16 pad)
  __shared__ int w2l[800];
  __shared__ int ws2l[16];
  int tid = threadIdx.x, blk = blockIdx.x;
  for (int i = tid; i < 800; i += 256) w2l[i] = w2pi[i];
  if (tid < 16) ws2l[tid] = wsum2[tid];

  float s1 = mxf[1] / 255.0f + 1e-12f;
  int b0 = blk * 16;
  const float4* tf = (const float4*)t1f;
  for (int it = 0; it < 19; ++it) {
    int g = it * 256 + tid;  // 4704 float4
    if (g < 4704) {
      int oc = g / 784, rem = g % 784;
      int img = rem / 49, f4 = rem % 49;
      float4 v = tf[(size_t)(oc * 8192 + b0 + img) * 49 + f4];
      int pos = f4 * 4;
      float vv[4] = {v.x, v.y, v.z, v.w};
#pragma unroll
      for (int c = 0; c < 4; ++c) {
        int pp = pos + c;
        int row = pp / 14, px = pp - row * 14;
        int q = (int)fminf(fmaxf(rintf(vv[c] / s1), 0.f), 255.f) - 128;
        t1l[img * 1584 + row * 112 + px * 8 + oc] = (char)q;
      }
    }
  }
  __syncthreads();

  float s = s1 * wsc[1];
  float lmax = 0.f;
  for (int it = 0; it < 3; ++it) {
    int u = it * 256 + tid;  // 640 units: pair fastest -> weight-LDS broadcast
    if (u < 640) {
      int pair = u & 7;
      int t = u >> 3;
      int ph = t % 5, img = t / 5;
      const char* base = &t1l[img * 1584 + ph * 224];
      int aA[2][10], aB[2][10];
#pragma unroll
      for (int g = 0; g < 2; ++g)
#pragma unroll
        for (int j = 0; j < 10; ++j) { aA[g][j] = 0; aB[g][j] = 0; }

#pragma unroll 1
      for (int r = 0; r < 6; ++r) {
        int p2[28];
        const uint4* rp = (const uint4*)(base + r * 112);
#pragma unroll
        for (int q = 0; q < 7; ++q) {
          uint4 uu = rp[q];
          p2[4 * q] = (int)uu.x; p2[4 * q + 1] = (int)uu.y;
          p2[4 * q + 2] = (int)uu.z; p2[4 * q + 3] = (int)uu.w;
        }
        if (r <= 4) {
#pragma unroll
          for (int tc = 0; tc < 5; ++tc) {
#pragma unroll
            for (int g = 0; g < 2; ++g) {
              int2 w = *(const int2*)&w2l[(pair * 2 + g) * 50 + r * 10 + 2 * tc];
#pragma unroll
              for (int j = 0; j < 10; ++j)
                aA[g][j] = dot4(p2[2 * (j + tc) + 1], w.y, dot4(p2[2 * (j + tc)], w.x, aA[g][j]));
            }
          }
        }
        if (r >= 1) {
#pragma unroll
          for (int tc = 0; tc < 5; ++tc) {
#pragma unroll
            for (int g = 0; g < 2; ++g) {
              int2 w = *(const int2*)&w2l[(pair * 2 + g) * 50 + (r - 1) * 10 + 2 * tc];
#pragma unroll
              for (int j = 0; j < 10; ++j)
                aB[g][j] = dot4(p2[2 * (j + tc) + 1], w.y, dot4(p2[2 * (j + tc)], w.x, aB[g][j]));
            }
          }
        }
      }
      int bg = b0 + img;
#pragma unroll
      for (int g = 0; g < 2; ++g) {
        int oc = pair * 2 + g;
        int off = 128 * ws2l[oc];  // un-centering
        float bq = rintf(b2[oc] / s) * s;
        float* orow = t2fb + (size_t)bg * 400 + oc * 25 + ph * 5;
#pragma unroll
        for (int j = 0; j < 5; ++j) {
          int m4 = max(max(aA[g][2 * j], aA[g][2 * j + 1]), max(aB[g][2 * j], aB[g][2 * j + 1]));
          float v = fmaxf((float)(m4 + off) * s + bq, 0.f);
          orow[j] = v;
          lmax = fmaxf(lmax, v);
        }
      }
    }
  }
  lmax = blockMax(lmax);
  if (tid == 0) atomicMax(mx2, __float_as_int(lmax));
}

// fused quantize-t2 + fc1 (R9-verified): stages fw1 raw floats inline, per-oc
// sums via dot4 rows, block = 32 images, grid 256.
__global__ __launch_bounds__(256) void k_fc1q(const float* __restrict__ t2fb, const float* __restrict__ fw1,
                                              const float* __restrict__ fb1, const float* __restrict__ mxf,
                                              const float* __restrict__ fw1bm, float* __restrict__ u,
                                              int* __restrict__ mx3) {
  __shared__ int wl[12000];  // 120 x 100 dwords
  __shared__ int xq[3200];   // 32 img x 100 dwords
  __shared__ int wsl[120];
  __shared__ float fwssh;
  int tid = threadIdx.x, blk = blockIdx.x;

  if (tid < 64) {  // reduce 16 slice maxes (identity 0 for lanes >= 16)
    float m = (tid < 16) ? fw1bm[tid] : 0.f;
    m = warpMax(m);
    if (tid == 0) fwssh = m / 127.0f + 1e-12f;
  }
  __syncthreads();
  float fws = fwssh;

  // stage + quantize fw1 (192 KB, L2-resident) into LDS
  const float4* w4 = (const float4*)fw1;
  for (int i = tid; i < 12000; i += 256) {
    float4 v = w4[i];
    int q0 = qclamp(v.x, fws), q1 = qclamp(v.y, fws), q2 = qclamp(v.z, fws), q3 = qclamp(v.w, fws);
    wl[i] = (q0 & 255) | ((q1 & 255) << 8) | ((q2 & 255) << 16) | ((q3 & 255) << 24);
  }

  float s2 = mxf[2] / 255.0f + 1e-12f;
  int b0 = blk * 32;
  const float4* tf = (const float4*)t2fb + (size_t)b0 * 100;
  for (int it = 0; it < 13; ++it) {
    int g = it * 256 + tid;  // 3200 float4
    if (g < 3200) {
      float4 v = tf[g];
      int q0 = (int)fminf(fmaxf(rintf(v.x / s2), 0.f), 255.f) - 128;
      int q1 = (int)fminf(fmaxf(rintf(v.y / s2), 0.f), 255.f) - 128;
      int q2 = (int)fminf(fmaxf(rintf(v.z / s2), 0.f), 255.f) - 128;
      int q3 = (int)fminf(fmaxf(rintf(v.w / s2), 0.f), 255.f) - 128;
      xq[g] = (q0 & 255) | ((q1 & 255) << 8) | ((q2 & 255) << 16) | ((q3 & 255) << 24);
    }
  }
  __syncthreads();

  if (tid < 120) {  // per-oc weight sum: own row, no atomics (exact int sum)
    int acc = 0;
    const int* row = &wl[tid * 100];
#pragma unroll
    for (int c = 0; c < 100; c += 4) {
      int4 wv = *(const int4*)&row[c];
      acc = dot4(wv.x, 0x01010101, acc);
      acc = dot4(wv.y, 0x01010101, acc);
      acc = dot4(wv.z, 0x01010101, acc);
      acc = dot4(wv.w, 0x01010101, acc);
    }
    wsl[tid] = acc;
  }
  __syncthreads();

  float s = s2 * fws;
  int img8 = tid >> 3, j = tid & 7;  // thread = (img, oc-lane)
  int acc[15];
#pragma unroll
  for (int seg = 0; seg < 15; ++seg) acc[seg] = 0;
#pragma unroll 1
  for (int kc = 0; kc < 5; ++kc) {
    int xr[20];
#pragma unroll
    for (int q = 0; q < 5; ++q) {
      int4 t = *(const int4*)&xq[img8 * 100 + kc * 20 + q * 4];
      xr[4 * q] = t.x; xr[4 * q + 1] = t.y; xr[4 * q + 2] = t.z; xr[4 * q + 3] = t.w;
    }
#pragma unroll
    for (int seg = 0; seg < 15; ++seg) {
      const int* wrow = &wl[(seg * 8 + j) * 100 + kc * 20];
#pragma unroll
      for (int q = 0; q < 20; q += 4) {
        int4 wv = *(const int4*)&wrow[q];
        acc[seg] = dot4(xr[q], wv.x, acc[seg]);
        acc[seg] = dot4(xr[q + 1], wv.y, acc[seg]);
        acc[seg] = dot4(xr[q + 2], wv.z, acc[seg]);
        acc[seg] = dot4(xr[q + 3], wv.w, acc[seg]);
      }
    }
  }
  float lmax = 0.f;
  int bg = b0 + img8;
#pragma unroll
  for (int seg = 0; seg < 15; ++seg) {
    int oc = seg * 8 + j;
    int tot = acc[seg] + 128 * wsl[oc];
    float bq = rintf(fb1[oc] / s) * s;
    float v = fmaxf((float)tot * s + bq, 0.f);
    u[(size_t)bg * 120 + oc] = v;
    lmax = fmaxf(lmax, v);
  }
  lmax = blockMax(lmax);
  if (tid == 0) atomicMax(mx3, __float_as_int(lmax));
}

// fc2: quantize u inline, * fw2i[10,120] -> out[B,10]. 128 blocks x 64.
__global__ __launch_bounds__(64) void k_fc2(const float* __restrict__ u, const float* __restrict__ fw2i,
                                            const float* __restrict__ fb2, const float* __restrict__ mxf,
                                            const float* __restrict__ wsc, float* __restrict__ out) {
  int b = blockIdx.x * 64 + threadIdx.x;
  float s3 = mxf[3] / 255.0f + 1e-12f;
  float s = s3 * wsc[3];
  float acc[10];
#pragma unroll
  for (int o = 0; o < 10; ++o) acc[o] = 0.f;
  const float4* ur = (const float4*)(u + (size_t)b * 120);
  for (int kk = 0; kk < 30; ++kk) {
    float4 v = ur[kk];
    float q0 = fminf(fmaxf(rintf(v.x / s3), 0.f), 255.f);
    float q1 = fminf(fmaxf(rintf(v.y / s3), 0.f), 255.f);
    float q2 = fminf(fmaxf(rintf(v.z / s3), 0.f), 255.f);
    float q3 = fminf(fmaxf(rintf(v.w / s3), 0.f), 255.f);
#pragma unroll
    for (int o = 0; o < 10; ++o) {
      const float4* wr = (const float4*)(fw2i + o * 120 + kk * 4);
      float4 wv = wr[0];
      acc[o] = fmaf(q0, wv.x, acc[o]);
      acc[o] = fmaf(q1, wv.y, acc[o]);
      acc[o] = fmaf(q2, wv.z, acc[o]);
      acc[o] = fmaf(q3, wv.w, acc[o]);
    }
  }
#pragma unroll
  for (int o = 0; o < 10; ++o) {
    float bq = rintf(fb2[o] / s) * s;
    out[(size_t)b * 10 + o] = acc[o] * s + bq;
  }
}

extern "C" void kernel_launch(void* const* d_in, const int* in_sizes, int n_in,
                              void* d_out, int out_size, void* d_ws, size_t ws_size,
                              hipStream_t stream) {
  const float* x = (const float*)d_in[0];
  const float* w1 = (const float*)d_in[1];
  const float* b1 = (const float*)d_in[2];
  const float* w2 = (const float*)d_in[3];
  const float* b2 = (const float*)d_in[4];
  const float* fw1 = (const float*)d_in[5];
  const float* fb1 = (const float*)d_in[6];
  const float* fw2 = (const float*)d_in[7];
  const float* fb2 = (const float*)d_in[8];

  char* ws = (char*)d_ws;
  int* mx = (int*)(ws + OFF_MAX);
  float* mxf = (float*)(ws + OFF_MAX);
  float* wsc = (float*)(ws + OFF_WSC);
  int* w1pi = (int*)(ws + OFF_W1P);
  int* w2pi = (int*)(ws + OFF_W2P);
  int* wsum2 = (int*)(ws + OFF_WS2);
  float* fw1bm = (float*)(ws + OFF_FW1B);
  float* fw2i = (float*)(ws + OFF_FW2I);
  float* xbmax = (float*)(ws + OFF_XBM);
  float* uf = (float*)(ws + OFF_UF);
  float* t2fb = (float*)(ws + OFF_T2F);
  float* t1f = (float*)(ws + OFF_T1F);
  float* out = (float*)d_out;

  k_prep<<<1043, 256, 0, stream>>>((const float4*)x, w1, w2, fw1, fw2, mx, wsc,
                                   w1pi, w2pi, fw2i, wsum2, fw1bm, xbmax);
  k_conv1x<<<2048, 256, 0, stream>>>((const float4*)x, w1pi, b1, xbmax, wsc, t1f, mx + 1);
  k_conv2q<<<512, 256, 0, stream>>>(t1f, w2pi, b2, mxf, wsc, wsum2, t2fb, mx + 2);
  k_fc1q<<<256, 256, 0, stream>>>(t2fb, fw1, fb1, mxf, fw1bm, uf, mx + 3);
  k_fc2<<<128, 64, 0, stream>>>(uf, fw2i, fb2, mxf, wsc, out);
}

// Round 14
// 157.601 us; speedup vs baseline: 1.1606x; 1.0040x over previous
//
#include <hip/hip_runtime.h>
#include <stdint.h>

#define DI __device__ __forceinline__

typedef __attribute__((ext_vector_type(4))) int i32x4;

// ---------------- workspace layout (bytes) ----------------
static constexpr size_t OFF_MAX  = 0;                     // int[4]: [1]t1 [2]t2 [3]u
static constexpr size_t OFF_WSC  = 64;                    // float[4] weight scales (idx 2 unused)
static constexpr size_t OFF_W1P  = 1024;                  // int[150]  conv1 w (c0,c1,c2,0) per tap
static constexpr size_t OFF_W2P  = 4096;                  // int[800]  conv2 w (c0..c3),(c4,c5,0,0) per tap
static constexpr size_t OFF_WS2  = 8192;                  // int[16]   conv2 per-oc weight sums
static constexpr size_t OFF_FW1B = 8704;                  // float[16] fw1 per-slice maxes (race-free)
static constexpr size_t OFF_FW2I = 212992;                // float[1200] fc2 int-valued weights
static constexpr size_t OFF_XBM  = 221184;                // float[1024] per-block |x| maxes (race-free)
static constexpr size_t OFF_UF   = 262144;                // float[983040] fc1 output
static constexpr size_t OFF_T2F  = OFF_UF + 4194304ull;   // float[3276800] [B][400]
static constexpr size_t OFF_T1F  = OFF_UF + 20971520ull;  // float[9633792] [6][B][196]

#if defined(__HIP_DEVICE_COMPILE__) && __has_builtin(__builtin_amdgcn_sdot4)
#define HAS_SDOT4 1
#else
#define HAS_SDOT4 0
#endif

DI int dot4(int a, int b, int c) {
#if HAS_SDOT4
  return __builtin_amdgcn_sdot4(a, b, c, false);
#else
  c += ((int)(a << 24) >> 24) * ((int)(b << 24) >> 24);
  c += ((int)(a << 16) >> 24) * ((int)(b << 16) >> 24);
  c += ((int)(a << 8) >> 24) * ((int)(b << 8) >> 24);
  c += ((int)a >> 24) * ((int)b >> 24);
  return c;
#endif
}

DI float warpMax(float v) {
#pragma unroll
  for (int o = 32; o > 0; o >>= 1) v = fmaxf(v, __shfl_down(v, o, 64));
  return v;
}

DI float blockMax(float v) {  // valid on thread 0
  __shared__ float sm[8];
  int lane = threadIdx.x & 63, w = threadIdx.x >> 6;
  v = warpMax(v);
  if (lane == 0) sm[w] = v;
  __syncthreads();
  if (w == 0) {
    int nw = blockDim.x >> 6;
    v = (lane < nw) ? sm[lane] : 0.0f;
    v = warpMax(v);
  }
  return v;
}

DI int qclamp(float v, float s) {
  return (int)fminf(fmaxf(rintf(v / s), -128.0f), 127.0f);
}

DI uint32_t pack3(float a, float b, float c, float s) {
  int qa = qclamp(a, s), qb = qclamp(b, s), qc = qclamp(c, s);
  return (uint32_t)(qa & 255) | ((uint32_t)(qb & 255) << 8) | ((uint32_t)(qc & 255) << 16);
}

// ---- prep (R12-verified): [0,1024) x absmax -> xbmax; [1024,1040) fw1 slices;
//      1040 = mx init + w1 pack; 1041 = w2 pack/wsum2; 1042 = fw2.
__global__ __launch_bounds__(256) void k_prep(const float4* __restrict__ x,
                                              const float* __restrict__ w1, const float* __restrict__ w2,
                                              const float* __restrict__ fw1, const float* __restrict__ fw2,
                                              int* __restrict__ mx, float* __restrict__ wsc,
                                              int* __restrict__ w1pi, int* __restrict__ w2pi,
                                              float* __restrict__ fw2i, int* __restrict__ wsum2,
                                              float* __restrict__ fw1bm, float* __restrict__ xbmax) {
  int tid = threadIdx.x;
  int bid = blockIdx.x;
  if (bid < 1024) {
    const int n4 = 6291456;
    float m = 0.f;
    for (int i = bid * 256 + tid; i < n4; i += 1024 * 256) {
      float4 v = x[i];
      m = fmaxf(m, fmaxf(fmaxf(fabsf(v.x), fabsf(v.y)), fmaxf(fabsf(v.z), fabsf(v.w))));
    }
    m = blockMax(m);
    if (tid == 0) xbmax[bid] = m;  // every slot written -> no init, no atomics
    return;
  }
  if (bid < 1040) {  // fw1 absmax, 16 parallel slices of 750 float4
    int sl = bid - 1024;
    const float4* f4 = (const float4*)fw1;
    float m = 0.f;
    for (int i = sl * 750 + tid; i < (sl + 1) * 750; i += 256) {
      float4 v = f4[i];
      m = fmaxf(m, fmaxf(fmaxf(fabsf(v.x), fabsf(v.y)), fmaxf(fabsf(v.z), fabsf(v.w))));
    }
    m = blockMax(m);
    if (tid == 0) fw1bm[sl] = m;  // race-free scratch
    return;
  }

  __shared__ float sbc;
  __shared__ int wsm[16];
  int wbid = bid - 1040;

  if (wbid == 0) {
    if (tid < 4) mx[tid] = 0;  // init running activation maxes (t1, t2, u)
    float m = 0.f;
    for (int i = tid; i < 450; i += 256) m = fmaxf(m, fabsf(w1[i]));
    m = blockMax(m);
    if (tid == 0) { sbc = m; wsc[0] = m / 127.0f + 1e-12f; }
    __syncthreads();
    float s = sbc / 127.0f + 1e-12f;
    if (tid < 150) {  // o*25 + tap -> (w_c0,w_c1,w_c2,0)
      int o = tid / 25, t = tid % 25;
      int q0 = qclamp(w1[o * 75 + 0 * 25 + t], s);
      int q1 = qclamp(w1[o * 75 + 1 * 25 + t], s);
      int q2 = qclamp(w1[o * 75 + 2 * 25 + t], s);
      w1pi[tid] = (q0 & 255) | ((q1 & 255) << 8) | ((q2 & 255) << 16);
    }
  } else if (wbid == 1) {
    float m = 0.0f;
    for (int i = tid; i < 2400; i += 256) m = fmaxf(m, fabsf(w2[i]));
    m = blockMax(m);
    if (tid == 0) { sbc = m; wsc[1] = m / 127.0f + 1e-12f; }
    if (tid < 16) wsm[tid] = 0;
    __syncthreads();
    float s = sbc / 127.0f + 1e-12f;
    for (int t0 = tid; t0 < 400; t0 += 256) {  // oc*25 + tap -> (c0..c3),(c4,c5,0,0)
      int o = t0 / 25, t = t0 % 25;
      int q0 = qclamp(w2[o * 150 + 0 * 25 + t], s);
      int q1 = qclamp(w2[o * 150 + 1 * 25 + t], s);
      int q2 = qclamp(w2[o * 150 + 2 * 25 + t], s);
      int q3 = qclamp(w2[o * 150 + 3 * 25 + t], s);
      int q4 = qclamp(w2[o * 150 + 4 * 25 + t], s);
      int q5 = qclamp(w2[o * 150 + 5 * 25 + t], s);
      w2pi[2 * t0] = (q0 & 255) | ((q1 & 255) << 8) | ((q2 & 255) << 16) | ((q3 & 255) << 24);
      w2pi[2 * t0 + 1] = (q4 & 255) | ((q5 & 255) << 8);
      atomicAdd(&wsm[o], q0 + q1 + q2 + q3 + q4 + q5);
    }
    __syncthreads();
    if (tid < 16) wsum2[tid] = wsm[tid];
  } else {
    float m = 0.0f;
    for (int i = tid; i < 1200; i += 256) m = fmaxf(m, fabsf(fw2[i]));
    m = blockMax(m);
    if (tid == 0) { sbc = m; wsc[3] = m / 127.0f + 1e-12f; }
    __syncthreads();
    float s = sbc / 127.0f + 1e-12f;
    for (int i = tid; i < 1200; i += 256)
      fw2i[i] = fminf(fmaxf(rintf(fw2[i] / s), -128.0f), 127.0f);
  }
}

// fused quantize-x + conv1 via MFMA i8. Block = 4 images; wave = 1 image.
// Tile = mfma_i32_16x16x64_i8 x2 (K=128 covers 25 taps x 4B dwords + pad):
//   M row m = 4*pooled + contributor (pool is lane-local in C: row=(lane>>4)*4+reg
//   -> lane's 4 regs are the 4 pool contributors of pooled (lane>>4)).
//   N col = oc (lane&15; 6 of 16 used). K byte = tap*4 + channel; the
//   (c0,c1,c2,0) dword-per-tap layout of xl/w1pi IS the K packing on both sides.
// Integer accumulation exact -> bit-identical to dot4 version.
__global__ __launch_bounds__(256) void k_conv1m(const float4* __restrict__ x4, const int* __restrict__ w1pi,
                                                const float* __restrict__ b1, const float* __restrict__ xbmax,
                                                const float* __restrict__ wsc, float* __restrict__ t1f,
                                                int* __restrict__ mx1) {
  __shared__ int xl[4608];  // 4 img x 32 rows x 36 dwords (pad 4/row)
  __shared__ float s0sh;
  int tid = threadIdx.x;
  int blk = blockIdx.x;
  int lane = tid & 63, wave = tid >> 6;

  float mxv = 0.f;
#pragma unroll
  for (int i = 0; i < 4; ++i) mxv = fmaxf(mxv, xbmax[i * 256 + tid]);
  mxv = blockMax(mxv);
  if (tid == 0) s0sh = mxv / 127.0f + 1e-12f;
  __syncthreads();
  float s0 = s0sh;

  // phase 1: quantize own 4 images into LDS (R12-verified)
  const float4* xb = x4 + (size_t)blk * 3072;  // 4 img * 768 float4
#pragma unroll
  for (int i = 0; i < 4; ++i) {
    int G = i * 256 + tid;  // 1024 px4-groups
    int img = G >> 8, p4 = G & 255;
    float4 va = xb[img * 768 + p4];
    float4 vb = xb[img * 768 + 256 + p4];
    float4 vc = xb[img * 768 + 512 + p4];
    int4 o;
    o.x = (int)pack3(va.x, vb.x, vc.x, s0);
    o.y = (int)pack3(va.y, vb.y, vc.y, s0);
    o.z = (int)pack3(va.z, vb.z, vc.z, s0);
    o.w = (int)pack3(va.w, vb.w, vc.w, s0);
    int row = p4 >> 3, cg = p4 & 7;
    *(int4*)&xl[img * 1152 + row * 36 + cg * 4] = o;
  }
  __syncthreads();

  float s = s0 * wsc[0];

  // per-lane constants
  int oc = lane & 15;
  int g = lane >> 4;            // K-group (A & B) AND pooled-idx in C
  int r16 = lane & 15;          // A-row
  int p_idx = r16 >> 2;         // pooled idx this lane FEEDS via A
  int ci = r16 & 3;             // pool contributor
  int drow = ci >> 1, dcol = ci & 1;

  // B fragments (weights) once: col=oc, taps g*4..g*4+3 per K-half
  i32x4 wb0, wb1;
  {
    int base = oc * 25;
    int t0 = g * 4;
    wb0.x = (oc < 6) ? w1pi[base + t0 + 0] : 0;
    wb0.y = (oc < 6) ? w1pi[base + t0 + 1] : 0;
    wb0.z = (oc < 6) ? w1pi[base + t0 + 2] : 0;
    wb0.w = (oc < 6) ? w1pi[base + t0 + 3] : 0;
    int t1 = 16 + g * 4;
    wb1.x = (oc < 6 && t1 + 0 < 25) ? w1pi[base + t1 + 0] : 0;
    wb1.y = (oc < 6 && t1 + 1 < 25) ? w1pi[base + t1 + 1] : 0;
    wb1.z = (oc < 6 && t1 + 2 < 25) ? w1pi[base + t1 + 2] : 0;
    wb1.w = (oc < 6 && t1 + 3 < 25) ? w1pi[base + t1 + 3] : 0;
  }

  // A tap offsets (loop-invariant per lane); pads masked to 0 after load
  int offA0[4], offA1[4];
  bool pad1[4];
#pragma unroll
  for (int j = 0; j < 4; ++j) {
    int t = g * 4 + j;  // 0..15, all real
    offA0[j] = (t / 5) * 36 + (t % 5);
    int t2 = 16 + g * 4 + j;  // 16..31; >24 is pad
    pad1[j] = (t2 > 24);
    int tt = pad1[j] ? 24 : t2;
    offA1[j] = (tt / 5) * 36 + (tt % 5);
  }

  float bqv;
  {
    int occ = (oc < 6) ? oc : 5;
    bqv = rintf(b1[occ] / s) * s;
  }

  int imgoff = wave * 1152;
  int bg = blk * 4 + wave;
  int pr = 0, pc = p_idx;  // pooled coords this lane feeds (A addressing)
  float lmax = 0.f;

#pragma unroll 1
  for (int tile = 0; tile < 49; ++tile) {
    int base = imgoff + (2 * pr + drow) * 36 + (2 * pc + dcol);
    i32x4 a0, a1;
    a0.x = xl[base + offA0[0]];
    a0.y = xl[base + offA0[1]];
    a0.z = xl[base + offA0[2]];
    a0.w = xl[base + offA0[3]];
    a1.x = pad1[0] ? 0 : xl[base + offA1[0]];
    a1.y = pad1[1] ? 0 : xl[base + offA1[1]];
    a1.z = pad1[2] ? 0 : xl[base + offA1[2]];
    a1.w = pad1[3] ? 0 : xl[base + offA1[3]];
    i32x4 acc = {0, 0, 0, 0};
    acc = __builtin_amdgcn_mfma_i32_16x16x64_i8(a0, wb0, acc, 0, 0, 0);
    acc = __builtin_amdgcn_mfma_i32_16x16x64_i8(a1, wb1, acc, 0, 0, 0);
    // pool: lane's 4 regs = 4 contributors of pooled output (tile*4 + g), col=oc
    int m = max(max(acc.x, acc.y), max(acc.z, acc.w));
    float v0 = fmaxf((float)m * s + bqv, 0.f);
    if (oc < 6) t1f[(size_t)(oc * 8192 + bg) * 196 + tile * 4 + g] = v0;
    lmax = fmaxf(lmax, (oc < 6) ? v0 : 0.f);
    pc += 4;
    if (pc >= 14) { pc -= 14; pr += 1; }
  }
  lmax = blockMax(lmax);
  if (tid == 0) atomicMax(mx1, __float_as_int(lmax));
}

// fused quantize-t1 + conv2: block = 16 images (R2-verified).
__global__ __launch_bounds__(256, 4) void k_conv2q(const float* __restrict__ t1f, const int* __restrict__ w2pi,
                                                   const float* __restrict__ b2, const float* __restrict__ mxf,
                                                   const float* __restrict__ wsc, const int* __restrict__ wsum2,
                                                   float* __restrict__ t2fb, int* __restrict__ mx2) {
  __shared__ char t1l[25344];  // 16 img x 1584 (14*112 + 16 pad)
  __shared__ int w2l[800];
  __shared__ int ws2l[16];
  int tid = threadIdx.x, blk = blockIdx.x;
  for (int i = tid; i < 800; i += 256) w2l[i] = w2pi[i];
  if (tid < 16) ws2l[tid] = wsum2[tid];

  float s1 = mxf[1] / 255.0f + 1e-12f;
  int b0 = blk * 16;
  const float4* tf = (const float4*)t1f;
  for (int it = 0; it < 19; ++it) {
    int g = it * 256 + tid;  // 4704 float4
    if (g < 4704) {
      int oc = g / 784, rem = g % 784;
      int img = rem / 49, f4 = rem % 49;
      float4 v = tf[(size_t)(oc * 8192 + b0 + img) * 49 + f4];
      int pos = f4 * 4;
      float vv[4] = {v.x, v.y, v.z, v.w};
#pragma unroll
      for (int c = 0; c < 4; ++c) {
        int pp = pos + c;
        int row = pp / 14, px = pp - row * 14;
        int q = (int)fminf(fmaxf(rintf(vv[c] / s1), 0.f), 255.f) - 128;
        t1l[img * 1584 + row * 112 + px * 8 + oc] = (char)q;
      }
    }
  }
  __syncthreads();

  float s = s1 * wsc[1];
  float lmax = 0.f;
  for (int it = 0; it < 3; ++it) {
    int u = it * 256 + tid;  // 640 units: pair fastest -> weight-LDS broadcast
    if (u < 640) {
      int pair = u & 7;
      int t = u >> 3;
      int ph = t % 5, img = t / 5;
      const char* base = &t1l[img * 1584 + ph * 224];
      int aA[2][10], aB[2][10];
#pragma unroll
      for (int g = 0; g < 2; ++g)
#pragma unroll
        for (int j = 0; j < 10; ++j) { aA[g][j] = 0; aB[g][j] = 0; }

#pragma unroll 1
      for (int r = 0; r < 6; ++r) {
        int p2[28];
        const uint4* rp = (const uint4*)(base + r * 112);
#pragma unroll
        for (int q = 0; q < 7; ++q) {
          uint4 uu = rp[q];
          p2[4 * q] = (int)uu.x; p2[4 * q + 1] = (int)uu.y;
          p2[4 * q + 2] = (int)uu.z; p2[4 * q + 3] = (int)uu.w;
        }
        if (r <= 4) {
#pragma unroll
          for (int tc = 0; tc < 5; ++tc) {
#pragma unroll
            for (int g = 0; g < 2; ++g) {
              int2 w = *(const int2*)&w2l[(pair * 2 + g) * 50 + r * 10 + 2 * tc];
#pragma unroll
              for (int j = 0; j < 10; ++j)
                aA[g][j] = dot4(p2[2 * (j + tc) + 1], w.y, dot4(p2[2 * (j + tc)], w.x, aA[g][j]));
            }
          }
        }
        if (r >= 1) {
#pragma unroll
          for (int tc = 0; tc < 5; ++tc) {
#pragma unroll
            for (int g = 0; g < 2; ++g) {
              int2 w = *(const int2*)&w2l[(pair * 2 + g) * 50 + (r - 1) * 10 + 2 * tc];
#pragma unroll
              for (int j = 0; j < 10; ++j)
                aB[g][j] = dot4(p2[2 * (j + tc) + 1], w.y, dot4(p2[2 * (j + tc)], w.x, aB[g][j]));
            }
          }
        }
      }
      int bg = b0 + img;
#pragma unroll
      for (int g = 0; g < 2; ++g) {
        int oc = pair * 2 + g;
        int off = 128 * ws2l[oc];  // un-centering
        float bq = rintf(b2[oc] / s) * s;
        float* orow = t2fb + (size_t)bg * 400 + oc * 25 + ph * 5;
#pragma unroll
        for (int j = 0; j < 5; ++j) {
          int m4 = max(max(aA[g][2 * j], aA[g][2 * j + 1]), max(aB[g][2 * j], aB[g][2 * j + 1]));
          float v = fmaxf((float)(m4 + off) * s + bq, 0.f);
          orow[j] = v;
          lmax = fmaxf(lmax, v);
        }
      }
    }
  }
  lmax = blockMax(lmax);
  if (tid == 0) atomicMax(mx2, __float_as_int(lmax));
}

// fused quantize-t2 + fc1 (R9-verified): stages fw1 raw floats inline, per-oc
// sums via dot4 rows, block = 32 images, grid 256.
__global__ __launch_bounds__(256) void k_fc1q(const float* __restrict__ t2fb, const float* __restrict__ fw1,
                                              const float* __restrict__ fb1, const float* __restrict__ mxf,
                                              const float* __restrict__ fw1bm, float* __restrict__ u,
                                              int* __restrict__ mx3) {
  __shared__ int wl[12000];  // 120 x 100 dwords
  __shared__ int xq[3200];   // 32 img x 100 dwords
  __shared__ int wsl[120];
  __shared__ float fwssh;
  int tid = threadIdx.x, blk = blockIdx.x;

  if (tid < 64) {  // reduce 16 slice maxes (identity 0 for lanes >= 16)
    float m = (tid < 16) ? fw1bm[tid] : 0.f;
    m = warpMax(m);
    if (tid == 0) fwssh = m / 127.0f + 1e-12f;
  }
  __syncthreads();
  float fws = fwssh;

  // stage + quantize fw1 (192 KB, L2-resident) into LDS
  const float4* w4 = (const float4*)fw1;
  for (int i = tid; i < 12000; i += 256) {
    float4 v = w4[i];
    int q0 = qclamp(v.x, fws), q1 = qclamp(v.y, fws), q2 = qclamp(v.z, fws), q3 = qclamp(v.w, fws);
    wl[i] = (q0 & 255) | ((q1 & 255) << 8) | ((q2 & 255) << 16) | ((q3 & 255) << 24);
  }

  float s2 = mxf[2] / 255.0f + 1e-12f;
  int b0 = blk * 32;
  const float4* tf = (const float4*)t2fb + (size_t)b0 * 100;
  for (int it = 0; it < 13; ++it) {
    int g = it * 256 + tid;  // 3200 float4
    if (g < 3200) {
      float4 v = tf[g];
      int q0 = (int)fminf(fmaxf(rintf(v.x / s2), 0.f), 255.f) - 128;
      int q1 = (int)fminf(fmaxf(rintf(v.y / s2), 0.f), 255.f) - 128;
      int q2 = (int)fminf(fmaxf(rintf(v.z / s2), 0.f), 255.f) - 128;
      int q3 = (int)fminf(fmaxf(rintf(v.w / s2), 0.f), 255.f) - 128;
      xq[g] = (q0 & 255) | ((q1 & 255) << 8) | ((q2 & 255) << 16) | ((q3 & 255) << 24);
    }
  }
  __syncthreads();

  if (tid < 120) {  // per-oc weight sum: own row, no atomics (exact int sum)
    int acc = 0;
    const int* row = &wl[tid * 100];
#pragma unroll
    for (int c = 0; c < 100; c += 4) {
      int4 wv = *(const int4*)&row[c];
      acc = dot4(wv.x, 0x01010101, acc);
      acc = dot4(wv.y, 0x01010101, acc);
      acc = dot4(wv.z, 0x01010101, acc);
      acc = dot4(wv.w, 0x01010101, acc);
    }
    wsl[tid] = acc;
  }
  __syncthreads();

  float s = s2 * fws;
  int img8 = tid >> 3, j = tid & 7;  // thread = (img, oc-lane)
  int acc[15];
#pragma unroll
  for (int seg = 0; seg < 15; ++seg) acc[seg] = 0;
#pragma unroll 1
  for (int kc = 0; kc < 5; ++kc) {
    int xr[20];
#pragma unroll
    for (int q = 0; q < 5; ++q) {
      int4 t = *(const int4*)&xq[img8 * 100 + kc * 20 + q * 4];
      xr[4 * q] = t.x; xr[4 * q + 1] = t.y; xr[4 * q + 2] = t.z; xr[4 * q + 3] = t.w;
    }
#pragma unroll
    for (int seg = 0; seg < 15; ++seg) {
      const int* wrow = &wl[(seg * 8 + j) * 100 + kc * 20];
#pragma unroll
      for (int q = 0; q < 20; q += 4) {
        int4 wv = *(const int4*)&wrow[q];
        acc[seg] = dot4(xr[q], wv.x, acc[seg]);
        acc[seg] = dot4(xr[q + 1], wv.y, acc[seg]);
        acc[seg] = dot4(xr[q + 2], wv.z, acc[seg]);
        acc[seg] = dot4(xr[q + 3], wv.w, acc[seg]);
      }
    }
  }
  float lmax = 0.f;
  int bg = b0 + img8;
#pragma unroll
  for (int seg = 0; seg < 15; ++seg) {
    int oc = seg * 8 + j;
    int tot = acc[seg] + 128 * wsl[oc];
    float bq = rintf(fb1[oc] / s) * s;
    float v = fmaxf((float)tot * s + bq, 0.f);
    u[(size_t)bg * 120 + oc] = v;
    lmax = fmaxf(lmax, v);
  }
  lmax = blockMax(lmax);
  if (tid == 0) atomicMax(mx3, __float_as_int(lmax));
}

// fc2: quantize u inline, * fw2i[10,120] -> out[B,10]. 128 blocks x 64.
__global__ __launch_bounds__(64) void k_fc2(const float* __restrict__ u, const float* __restrict__ fw2i,
                                            const float* __restrict__ fb2, const float* __restrict__ mxf,
                                            const float* __restrict__ wsc, float* __restrict__ out) {
  int b = blockIdx.x * 64 + threadIdx.x;
  float s3 = mxf[3] / 255.0f + 1e-12f;
  float s = s3 * wsc[3];
  float acc[10];
#pragma unroll
  for (int o = 0; o < 10; ++o) acc[o] = 0.f;
  const float4* ur = (const float4*)(u + (size_t)b * 120);
  for (int kk = 0; kk < 30; ++kk) {
    float4 v = ur[kk];
    float q0 = fminf(fmaxf(rintf(v.x / s3), 0.f), 255.f);
    float q1 = fminf(fmaxf(rintf(v.y / s3), 0.f), 255.f);
    float q2 = fminf(fmaxf(rintf(v.z / s3), 0.f), 255.f);
    float q3 = fminf(fmaxf(rintf(v.w / s3), 0.f), 255.f);
#pragma unroll
    for (int o = 0; o < 10; ++o) {
      const float4* wr = (const float4*)(fw2i + o * 120 + kk * 4);
      float4 wv = wr[0];
      acc[o] = fmaf(q0, wv.x, acc[o]);
      acc[o] = fmaf(q1, wv.y, acc[o]);
      acc[o] = fmaf(q2, wv.z, acc[o]);
      acc[o] = fmaf(q3, wv.w, acc[o]);
    }
  }
#pragma unroll
  for (int o = 0; o < 10; ++o) {
    float bq = rintf(fb2[o] / s) * s;
    out[(size_t)b * 10 + o] = acc[o] * s + bq;
  }
}

extern "C" void kernel_launch(void* const* d_in, const int* in_sizes, int n_in,
                              void* d_out, int out_size, void* d_ws, size_t ws_size,
                              hipStream_t stream) {
  const float* x = (const float*)d_in[0];
  const float* w1 = (const float*)d_in[1];
  const float* b1 = (const float*)d_in[2];
  const float* w2 = (const float*)d_in[3];
  const float* b2 = (const float*)d_in[4];
  const float* fw1 = (const float*)d_in[5];
  const float* fb1 = (const float*)d_in[6];
  const float* fw2 = (const float*)d_in[7];
  const float* fb2 = (const float*)d_in[8];

  char* ws = (char*)d_ws;
  int* mx = (int*)(ws + OFF_MAX);
  float* mxf = (float*)(ws + OFF_MAX);
  float* wsc = (float*)(ws + OFF_WSC);
  int* w1pi = (int*)(ws + OFF_W1P);
  int* w2pi = (int*)(ws + OFF_W2P);
  int* wsum2 = (int*)(ws + OFF_WS2);
  float* fw1bm = (float*)(ws + OFF_FW1B);
  float* fw2i = (float*)(ws + OFF_FW2I);
  float* xbmax = (float*)(ws + OFF_XBM);
  float* uf = (float*)(ws + OFF_UF);
  float* t2fb = (float*)(ws + OFF_T2F);
  float* t1f = (float*)(ws + OFF_T1F);
  float* out = (float*)d_out;

  k_prep<<<1043, 256, 0, stream>>>((const float4*)x, w1, w2, fw1, fw2, mx, wsc,
                                   w1pi, w2pi, fw2i, wsum2, fw1bm, xbmax);
  k_conv1m<<<2048, 256, 0, stream>>>((const float4*)x, w1pi, b1, xbmax, wsc, t1f, mx + 1);
  k_conv2q<<<512, 256, 0, stream>>>(t1f, w2pi, b2, mxf, wsc, wsum2, t2fb, mx + 2);
  k_fc1q<<<256, 256, 0, stream>>>(t2fb, fw1, fb1, mxf, fw1bm, uf, mx + 3);
  k_fc2<<<128, 64, 0, stream>>>(uf, fw2i, fb2, mxf, wsc, out);
}